// Round 1
// baseline (430.196 us; speedup 1.0000x reference)
//
#include <hip/hip_runtime.h>
#include <math.h>

// GRU-D, diagonal weights: independent scalar recurrence per (b,f) over T.
// R2: kill the barrier-coupled producer/consumer pipeline. rocprof showed
// VALUBusy 27% / HBM 27% / occupancy 19.5% -> latency-bound on the per-chunk
// __syncthreads drain (vmcnt(0) re-paid 32x, loads never pipelined across
// chunks). New structure: one thread per (b,f) chain, inputs streamed
// directly into a CH=16-step register double-buffer, 2x-unrolled chunk loop
// so chunk k+2's loads are in flight while chunk k+1 computes. No LDS, no
// barriers, no loader waves. Lane f -> consecutive addresses: every global
// access is a fully-coalesced 256B wave transaction. Nontemporal stores keep
// the write-once output from evicting the input stream in L2/L3.

#define TT 512
#define BB 256
#define FF 256
#define BF (BB * FF)        // elements per time step per array
#define CH 16               // steps per register chunk
#define NCH (TT / CH)       // 32 chunks

__device__ __forceinline__ float fast_sigmoid(float x) {
    return __builtin_amdgcn_rcpf(1.0f + __expf(-x));
}
__device__ __forceinline__ float fast_tanh(float x) {
    return fmaf(-2.0f, __builtin_amdgcn_rcpf(1.0f + __expf(2.0f * x)), 1.0f);
}

__global__ __launch_bounds__(256, 1) void grud_kernel(
    const float* __restrict__ X, const float* __restrict__ Mask,
    const float* __restrict__ Delta,
    const float* __restrict__ x_mean,
    const float* __restrict__ w_dg_x, const float* __restrict__ b_dg_x,
    const float* __restrict__ w_dg_h, const float* __restrict__ b_dg_h,
    const float* __restrict__ w_xz, const float* __restrict__ u_hz,
    const float* __restrict__ b_z,
    const float* __restrict__ w_xr, const float* __restrict__ u_hr,
    const float* __restrict__ b_r,
    const float* __restrict__ w_xh, const float* __restrict__ u_hh,
    const float* __restrict__ v_mh, const float* __restrict__ b_h,
    float* __restrict__ out)
{
    const int f = threadIdx.x;          // 0..255 : feature index
    const int b = blockIdx.x;           // batch index

    const size_t base = (size_t)b * FF + f;
    const float* __restrict__ px = X     + base;
    const float* __restrict__ pm = Mask  + base;
    const float* __restrict__ pd = Delta + base;
    float* __restrict__ ob = out + (size_t)b * TT * FF + f;

    // per-feature parameters (L2-resident, coalesced)
    const float xm  = x_mean[f];
    const float wdx = w_dg_x[f], bdx = b_dg_x[f];
    const float wdh = w_dg_h[f], bdh = b_dg_h[f];
    const float wxz = w_xz[f],   uhz = u_hz[f], bz = b_z[f];
    const float wxr = w_xr[f],   uhr = u_hr[f], br = b_r[f];
    const float wxh = w_xh[f],   uhh = u_hh[f];
    const float vmh = v_mh[f],   bh  = b_h[f];

    // two register chunk-buffers (2 * 3 * 16 = 96 VGPRs of payload)
    float ax[CH], am[CH], ad[CH];
    float ex[CH], em[CH], ed[CH];
    float h = 0.0f;

    auto loadc = [&](float (&dx)[CH], float (&dm)[CH], float (&dd)[CH], int k0) {
        const size_t o = (size_t)k0 * CH * BF;
        #pragma unroll
        for (int s = 0; s < CH; ++s) dx[s] = px[o + (size_t)s * BF];
        #pragma unroll
        for (int s = 0; s < CH; ++s) dm[s] = pm[o + (size_t)s * BF];
        #pragma unroll
        for (int s = 0; s < CH; ++s) dd[s] = pd[o + (size_t)s * BF];
    };

    auto computec = [&](float (&dx)[CH], float (&dm)[CH], float (&dd)[CH], int k0) {
        float* op = ob + (size_t)k0 * CH * FF;
        #pragma unroll
        for (int s = 0; s < CH; ++s) {
            float x = dx[s], m = dm[s], d = dd[s];
            float gx = __expf(-fmaxf(0.0f, fmaf(wdx, d, bdx)));
            float gh = __expf(-fmaxf(0.0f, fmaf(wdh, d, bdh)));
            float xhat = fmaf(gx, x, (1.0f - gx) * xm);
            x = fmaf(m, x, (1.0f - m) * xhat);
            h = gh * h;
            float z  = fast_sigmoid(fmaf(wxz, x, fmaf(uhz, h, bz)));
            float r  = fast_sigmoid(fmaf(wxr, x, fmaf(uhr, h, br)));
            float ht = fast_tanh(fmaf(wxh, x, fmaf(uhh, r * h, fmaf(vmh, m, bh))));
            h = fmaf(z, ht - h, h);               // (1-z)*h + z*ht
            __builtin_nontemporal_store(h, op + (size_t)s * FF);
        }
    };

    // prologue: chunks 0 and 1 in flight before any compute
    loadc(ax, am, ad, 0);
    loadc(ex, em, ed, 1);

    // steady state: compute(k) | issue(k+2) | compute(k+1) | issue(k+3)
    // -> one full chunk of loads always in flight, never drained by barriers
    for (int k = 0; k < NCH - 2; k += 2) {
        computec(ax, am, ad, k);
        loadc(ax, am, ad, k + 2);
        computec(ex, em, ed, k + 1);
        loadc(ex, em, ed, k + 3);       // k <= 28 -> k+3 <= 31, always valid
    }
    // tail: chunks 30, 31 already resident
    computec(ax, am, ad, NCH - 2);
    computec(ex, em, ed, NCH - 1);

    // second output: last hidden state [B, H]
    out[(size_t)BB * TT * FF + (size_t)b * FF + f] = h;
}

extern "C" void kernel_launch(void* const* d_in, const int* in_sizes, int n_in,
                              void* d_out, int out_size, void* d_ws, size_t ws_size,
                              hipStream_t stream) {
    const float* X      = (const float*)d_in[0];
    const float* Mask   = (const float*)d_in[1];
    const float* Delta  = (const float*)d_in[2];
    const float* x_mean = (const float*)d_in[3];
    const float* w_dg_x = (const float*)d_in[4];
    const float* b_dg_x = (const float*)d_in[5];
    const float* w_dg_h = (const float*)d_in[6];
    const float* b_dg_h = (const float*)d_in[7];
    const float* w_xz   = (const float*)d_in[8];
    const float* u_hz   = (const float*)d_in[9];
    const float* b_z    = (const float*)d_in[10];
    const float* w_xr   = (const float*)d_in[11];
    const float* u_hr   = (const float*)d_in[12];
    const float* b_r    = (const float*)d_in[13];
    const float* w_xh   = (const float*)d_in[14];
    const float* u_hh   = (const float*)d_in[15];
    const float* v_mh   = (const float*)d_in[16];
    const float* b_h    = (const float*)d_in[17];
    float* out = (float*)d_out;

    grud_kernel<<<BB, 256, 0, stream>>>(
        X, Mask, Delta, x_mean, w_dg_x, b_dg_x, w_dg_h, b_dg_h,
        w_xz, u_hz, b_z, w_xr, u_hr, b_r, w_xh, u_hh, v_mh, b_h, out);
}